// Round 21
// baseline (39.210 us; speedup 1.0000x reference)
//
#include <hip/hip_runtime.h>

// ADDA local attention, K=3, dilation=1, head_dim=64.
// q,k,v = [B=8, d=512, H=56, W=56] fp32 (channel-major), out = [B,H,W,512] fp32.
//
// R21: x-split waves — combine R15's load economy with 2x wave count.
//  wave = (row-pair, x-half); lanes = 2 rows x 30 cols (28 px + 2 halo),
//  lane = r*32 + xc. Per channel per lane: k_own + k_outer + q loads
//  (v likewise) -> same loads/px as R15, but 3584 waves = 14/CU.
//  Vertical tap = __shfl_xor(own,32) (partner row); horizontal taps = DPP
//  (cross-row leakage only in unused halo-lane taps). 1 px/lane halves
//  per-lane VALU. Lane owns its pixel's FULL 64-ch output (R13 lesson);
//  TSTR=36 transpose + full-128B-line READOUT per 32-ch half (R15-proven).
//  Masks only at true image edges; the x-half seam halo holds real data.

namespace {

constexpr int HD = 64, HH = 56, WW = 56, HW = HH * WW;
constexpr int CS = HW, DTOT = 512;
constexpr float SCALE = 0.125f;
constexpr int TSTR = 36;       // px stride in transpose LDS (144B = 9x16B)

// value of this row at x-1 (lane i <- lane i-1): wave_shr:1 = 0x138
__device__ __forceinline__ float tapLf(float v) {
  int i = __float_as_int(v);
  return __int_as_float(__builtin_amdgcn_update_dpp(i, i, 0x138, 0xF, 0xF, false));
}
// value of this row at x+1 (lane i <- lane i+1): wave_shl:1 = 0x130
__device__ __forceinline__ float tapRf(float v) {
  int i = __float_as_int(v);
  return __int_as_float(__builtin_amdgcn_update_dpp(i, i, 0x130, 0xF, 0xF, false));
}

__global__ __launch_bounds__(64, 4)
void adda_fwd(const float* __restrict__ qg, const float* __restrict__ kg,
              const float* __restrict__ vg, float* __restrict__ outg) {
  __shared__ float tbuf[56 * TSTR];    // 8064 B: [pxw][32-ch half]

  // XCD-aware bijective swizzle (nwg = 3584 = 8*448)
  int wg = (int)blockIdx.x;
  const int nwg = (int)gridDim.x;
  if ((nwg & 7) == 0) wg = (wg & 7) * (nwg >> 3) + (wg >> 3);

  const int bh  = wg / 56;             // b*8 + head
  const int rem = wg - bh * 56;
  const int pair = rem >> 1;           // 0..27
  const int h    = rem & 1;            // x-half
  const int l    = (int)threadIdx.x;   // 0..63
  const int r    = l >> 5;             // row within pair
  const int xc   = l & 31;             // 0..29 used (0 and 29 are halo)
  const int y    = pair * 2;
  const int yown = y + r;
  const int x    = h * 28 - 1 + xc;    // this lane's x (halo: -1 / 56 / 27 / 56)
  const int xg   = x < 0 ? 0 : (x > WW - 1 ? WW - 1 : x);  // clamped (masked)
  const int yout = r ? (y + 2 > HH - 1 ? HH - 1 : y + 2)
                     : (y > 0 ? y - 1 : 0);                // clamped (masked)

  const long base = (long)bh * HD * HW;
  const float* __restrict__ qp  = qg + base + (long)yown * WW + xg;
  const float* __restrict__ kop = kg + base + (long)yown * WW + xg;  // own row
  const float* __restrict__ kxp = kg + base + (long)yout * WW + xg;  // outer row
  const float* __restrict__ vop = vg + base + (long)yown * WW + xg;
  const float* __restrict__ vxp = vg + base + (long)yout * WW + xg;

  float lg[9];
#pragma unroll
  for (int n = 0; n < 9; ++n) lg[n] = 0.f;

  // ---- 8-channel slabs, ping-pong (24 loads per k slab, 16 per v slab) ----
  float koA[8], kxA[8], qqA[8];
  float koB[8], kxB[8], qqB[8];
  float voA[8], vxA[8];
  float voB[8], vxB[8];

#define LOADK(S, cb)                                    \
  _Pragma("unroll") for (int i = 0; i < 8; ++i) {       \
    qq##S[i] = qp[((cb) + i) * CS];                     \
    ko##S[i] = kop[((cb) + i) * CS];                    \
    kx##S[i] = kxp[((cb) + i) * CS];                    \
  }
  // taps rows: above = r ? partner_own : outer ; below = r ? outer : partner_own
#define CONSK(S)                                        \
  _Pragma("unroll") for (int i = 0; i < 8; ++i) {       \
    const float swp = __shfl_xor(ko##S[i], 32);         \
    const float abv = r ? swp : kx##S[i];               \
    const float blw = r ? kx##S[i] : swp;               \
    const float own = ko##S[i];                         \
    const float qv  = qq##S[i];                         \
    lg[0] = fmaf(qv, tapLf(abv), lg[0]);                \
    lg[1] = fmaf(qv, abv,        lg[1]);                \
    lg[2] = fmaf(qv, tapRf(abv), lg[2]);                \
    lg[3] = fmaf(qv, tapLf(own), lg[3]);                \
    lg[4] = fmaf(qv, own,        lg[4]);                \
    lg[5] = fmaf(qv, tapRf(own), lg[5]);                \
    lg[6] = fmaf(qv, tapLf(blw), lg[6]);                \
    lg[7] = fmaf(qv, blw,        lg[7]);                \
    lg[8] = fmaf(qv, tapRf(blw), lg[8]);                \
  }
#define LOADV(S, cb)                                    \
  _Pragma("unroll") for (int i = 0; i < 8; ++i) {       \
    vo##S[i] = vop[((cb) + i) * CS];                    \
    vx##S[i] = vxp[((cb) + i) * CS];                    \
  }

  // ---- pass 1: 8 k slabs ----
  LOADK(A, 0);  LOADK(B, 8);
  CONSK(A); LOADK(A, 16);
  CONSK(B); LOADK(B, 24);
  CONSK(A); LOADK(A, 32);
  CONSK(B); LOADK(B, 40);
  CONSK(A); LOADK(A, 48);
  CONSK(B); LOADK(B, 56);
  CONSK(A); LOADV(A, 0);   // v prologue: latency hides under softmax
  CONSK(B); LOADV(B, 8);

  // ---- softmax (zero-padded unfold: OOB logit = exact 0) ----
  const bool okt = r ? true : (y > 0);
  const bool okb = r ? (y + 2 < HH) : true;
  const bool okl = x > 0;
  const bool okr = x < WW - 1;
  const bool ok[9] = {okt && okl, okt, okt && okr,
                      okl,        true, okr,
                      okb && okl, okb, okb && okr};
  float w[9];
  float mx = 0.f;
#pragma unroll
  for (int n = 0; n < 9; ++n) { w[n] = ok[n] ? lg[n] * SCALE : 0.f; mx = fmaxf(mx, w[n]); }
  float sum = 0.f;
#pragma unroll
  for (int n = 0; n < 9; ++n) { w[n] = __expf(w[n] - mx); sum += w[n]; }
  const float inv = 1.f / sum;
#pragma unroll
  for (int n = 0; n < 9; ++n) w[n] = ok[n] ? w[n] * inv : 0.f;  // OOB v = 0

  // ---- pass 2: 8 v slabs; f4 transpose writes; 32-ch half READOUTs ----
  const bool pxv = (xc >= 1) && (xc <= 28);
  const int pxw = r * 28 + xc - 1;     // 0..55 (valid lanes)

#define CONSV(S, cb)                                    \
  {                                                     \
    float o[8];                                         \
    _Pragma("unroll") for (int i = 0; i < 8; ++i) {     \
      const float swp = __shfl_xor(vo##S[i], 32);       \
      const float abv = r ? swp : vx##S[i];             \
      const float blw = r ? vx##S[i] : swp;             \
      const float own = vo##S[i];                       \
      float a = w[0] * tapLf(abv);                      \
      a = fmaf(w[1], abv,        a);                    \
      a = fmaf(w[2], tapRf(abv), a);                    \
      a = fmaf(w[3], tapLf(own), a);                    \
      a = fmaf(w[4], own,        a);                    \
      a = fmaf(w[5], tapRf(own), a);                    \
      a = fmaf(w[6], tapLf(blw), a);                    \
      a = fmaf(w[7], blw,        a);                    \
      a = fmaf(w[8], tapRf(blw), a);                    \
      o[i] = a;                                         \
    }                                                   \
    if (pxv) {                                          \
      const int cl = (cb) & 31;                         \
      *(float4*)&tbuf[pxw * TSTR + cl]     = make_float4(o[0], o[1], o[2], o[3]); \
      *(float4*)&tbuf[pxw * TSTR + cl + 4] = make_float4(o[4], o[5], o[6], o[7]); \
    }                                                   \
  }

  // out base: (b, row y, x = h*28), channel head*64
  float* __restrict__ ob =
      outg + ((long)(bh >> 3) * HW + (long)y * WW + h * 28) * DTOT + (bh & 7) * HD;

  // read-out of one 32-ch half: 56 px x 8 f4 = 448 f4 = 7 exact rounds.
  // pxw < 28 -> row y at x offset pxw; else row y+1 (global px +56-28).
#define READOUT(ch0)                                    \
  _Pragma("unroll") for (int rr = 0; rr < 7; ++rr) {    \
    const int g = rr * 64 + l;                          \
    const int pw = g >> 3, slot = g & 7;                \
    const int pa = pw + ((pw >= 28) ? 28 : 0);          \
    const float4 tv = *(const float4*)&tbuf[pw * TSTR + slot * 4]; \
    *(float4*)(ob + (long)pa * DTOT + (ch0) + slot * 4) = tv;      \
  }

  CONSV(A, 0);  LOADV(A, 16);
  CONSV(B, 8);  LOADV(B, 24);
  CONSV(A, 16); LOADV(A, 32);
  CONSV(B, 24); LOADV(B, 40);
  READOUT(0);
  CONSV(A, 32); LOADV(A, 48);
  CONSV(B, 40); LOADV(B, 56);
  CONSV(A, 48);
  CONSV(B, 56);
  READOUT(32);

#undef LOADK
#undef CONSK
#undef LOADV
#undef CONSV
#undef READOUT
}

} // namespace

extern "C" void kernel_launch(void* const* d_in, const int* in_sizes, int n_in,
                              void* d_out, int out_size, void* d_ws, size_t ws_size,
                              hipStream_t stream) {
  const float* q = (const float*)d_in[0];
  const float* k = (const float*)d_in[1];
  const float* v = (const float*)d_in[2];
  float* out = (float*)d_out;

  const int BH = in_sizes[0] / (HD * HW);  // B * 8 heads = 64
  dim3 grid(BH * 56);                       // 3584 = 8 * 448
  adda_fwd<<<grid, 64, 0, stream>>>(q, k, v, out);
}

// Round 22
// 37.999 us; speedup vs baseline: 1.0319x; 1.0319x over previous
//
#include <hip/hip_runtime.h>

// ADDA local attention, K=3, dilation=1, head_dim=64.
// q,k,v = [B=8, d=512, H=56, W=56] fp32 (channel-major), out = [B,H,W,512] fp32.
//
// R22 = R15 structure with f2 loads via lane=(row, pixel-pair) geometry:
//  - single 64-lane wave/block, grid 1792 (bh x 28 row-pairs), XCD swizzle
//  - lane l: r=l>>5 (row within pair), p=min(l&31,27) (pixel pair, 28 active)
//  - each lane loads float2 {2p,2p+1} for its OWN 3 tap rows + q:
//    pass1 = 4 f2-instrs/ch (vs R15's 6 dwords), pass2 = 3 (vs 4)
//    -> 448 VMEM/wave vs 640 (-30%), no shfl, no exchange
//    (middle tap rows loaded by both lane groups -> same-wave L1 hits)
//  - horizontal taps: 2 DPP per row; lane-group seam garbage only reaches
//    image-edge-masked taps (p=0 left, p=27 right)
//  - tbuf f4 writes (2-way bank alias), TSTR=36, full-128B-line READOUT
//  - masks at softmax only (zero-padded unfold: OOB logit = exact 0)

namespace {

constexpr int HD = 64, HH = 56, WW = 56, HW = HH * WW;
constexpr int CS = HW, DTOT = 512;
constexpr float SCALE = 0.125f;
constexpr int NP   = HH / 2;   // 28 row-pairs
constexpr int TSTR = 36;       // px stride in transpose LDS (144B = 9x16B)

// value of this row at x-1 (lane i <- lane i-1): wave_shr:1 = 0x138
__device__ __forceinline__ float tapLf(float v) {
  int i = __float_as_int(v);
  return __int_as_float(__builtin_amdgcn_update_dpp(i, i, 0x138, 0xF, 0xF, false));
}
// value of this row at x+1 (lane i <- lane i+1): wave_shl:1 = 0x130
__device__ __forceinline__ float tapRf(float v) {
  int i = __float_as_int(v);
  return __int_as_float(__builtin_amdgcn_update_dpp(i, i, 0x130, 0xF, 0xF, false));
}

__global__ __launch_bounds__(64, 2)
void adda_fwd(const float* __restrict__ qg, const float* __restrict__ kg,
              const float* __restrict__ vg, float* __restrict__ outg) {
  __shared__ float tbuf[112 * TSTR];   // 16128 B: [r*56 + x][32-ch half]

  // XCD-aware bijective swizzle (nwg = 1792 = 8*224)
  int wg = (int)blockIdx.x;
  const int nwg = (int)gridDim.x;
  if ((nwg & 7) == 0) wg = (wg & 7) * (nwg >> 3) + (wg >> 3);

  const int pair = wg % NP;
  const int bh   = wg / NP;            // b*8 + head
  const int l    = (int)threadIdx.x;   // 0..63
  const int r    = l >> 5;             // row within pair
  const int pl   = l & 31;
  const int p    = pl < 28 ? pl : 27;  // pixel pair (idle lanes clone p=27)
  const bool act = pl < 28;
  const int y    = pair * 2;
  const int yown = y + r;              // this lane's output row
  const int x0   = 2 * p;              // pixels x0, x0+1

  const long base = (long)bh * HD * HW;
  const int rA = (yown > 0) ? yown - 1 : 0;            // clamped; masked
  const int rC = (yown < HH - 1) ? yown + 1 : HH - 1;  // clamped; masked

  const float* __restrict__ qp  = qg + base + (long)yown * WW + x0;
  const float* __restrict__ kap = kg + base + (long)rA * WW + x0;
  const float* __restrict__ kbp = kg + base + (long)yown * WW + x0;
  const float* __restrict__ kcp = kg + base + (long)rC * WW + x0;
  const float* __restrict__ vap = vg + base + (long)rA * WW + x0;
  const float* __restrict__ vbp = vg + base + (long)yown * WW + x0;
  const float* __restrict__ vcp = vg + base + (long)rC * WW + x0;

  // logits: px0 = lg[0..8], px1 = lg[9..17]
  float lg[18];
#pragma unroll
  for (int n = 0; n < 18; ++n) lg[n] = 0.f;

  // ---- 8-channel slabs, ping-pong (32 f2-loads per k slab, 24 per v) ----
  float2 qA[8], aA[8], bA[8], cA[8];
  float2 qB[8], aB[8], bB[8], cB[8];

#define LOADK(S, cb)                                    \
  _Pragma("unroll") for (int i = 0; i < 8; ++i) {       \
    const int co = ((cb) + i) * CS;                     \
    q##S[i] = *(const float2*)(qp + co);                \
    a##S[i] = *(const float2*)(kap + co);               \
    b##S[i] = *(const float2*)(kbp + co);               \
    c##S[i] = *(const float2*)(kcp + co);               \
  }
  // px0 (x=x0): taps per row = {tapL(.y)=x0-1, .x, .y}
  // px1 (x=x0+1): taps per row = {.x, .y, tapR(.x)=x0+2}
#define CONSK(S)                                        \
  _Pragma("unroll") for (int i = 0; i < 8; ++i) {       \
    const float2 qv = q##S[i];                          \
    const float2 A = a##S[i], B2 = b##S[i], C = c##S[i];\
    const float tlA = tapLf(A.y),  trA = tapRf(A.x);    \
    const float tlB = tapLf(B2.y), trB = tapRf(B2.x);   \
    const float tlC = tapLf(C.y),  trC = tapRf(C.x);    \
    lg[0]  = fmaf(qv.x, tlA,  lg[0]);                   \
    lg[1]  = fmaf(qv.x, A.x,  lg[1]);                   \
    lg[2]  = fmaf(qv.x, A.y,  lg[2]);                   \
    lg[3]  = fmaf(qv.x, tlB,  lg[3]);                   \
    lg[4]  = fmaf(qv.x, B2.x, lg[4]);                   \
    lg[5]  = fmaf(qv.x, B2.y, lg[5]);                   \
    lg[6]  = fmaf(qv.x, tlC,  lg[6]);                   \
    lg[7]  = fmaf(qv.x, C.x,  lg[7]);                   \
    lg[8]  = fmaf(qv.x, C.y,  lg[8]);                   \
    lg[9]  = fmaf(qv.y, A.x,  lg[9]);                   \
    lg[10] = fmaf(qv.y, A.y,  lg[10]);                  \
    lg[11] = fmaf(qv.y, trA,  lg[11]);                  \
    lg[12] = fmaf(qv.y, B2.x, lg[12]);                  \
    lg[13] = fmaf(qv.y, B2.y, lg[13]);                  \
    lg[14] = fmaf(qv.y, trB,  lg[14]);                  \
    lg[15] = fmaf(qv.y, C.x,  lg[15]);                  \
    lg[16] = fmaf(qv.y, C.y,  lg[16]);                  \
    lg[17] = fmaf(qv.y, trC,  lg[17]);                  \
  }

  float2 vaA[8], vbA[8], vcA[8];
  float2 vaB[8], vbB[8], vcB[8];
#define LOADV(S, cb)                                    \
  _Pragma("unroll") for (int i = 0; i < 8; ++i) {       \
    const int co = ((cb) + i) * CS;                     \
    va##S[i] = *(const float2*)(vap + co);              \
    vb##S[i] = *(const float2*)(vbp + co);              \
    vc##S[i] = *(const float2*)(vcp + co);              \
  }

  // ---- pass 1: 8 k slabs, ping-pong ----
  LOADK(A, 0);  LOADK(B, 8);
  CONSK(A); LOADK(A, 16);
  CONSK(B); LOADK(B, 24);
  CONSK(A); LOADK(A, 32);
  CONSK(B); LOADK(B, 40);
  CONSK(A); LOADK(A, 48);
  CONSK(B); LOADK(B, 56);
  CONSK(A); LOADV(A, 0);   // v prologue: latency hides under softmax
  CONSK(B); LOADV(B, 8);

  // ---- 2 softmaxes (px0, px1); zero-padded unfold: OOB logit = exact 0 ----
  const bool okA = (yown > 0);
  const bool okC = (yown < HH - 1);
  const bool okl = (p > 0);        // px0's left tap
  const bool okr = (p < 27);       // px1's right tap
  const bool ok0[9] = {okA && okl, okA, okA,
                       okl,        true, true,
                       okC && okl, okC, okC};
  const bool ok1[9] = {okA, okA, okA && okr,
                       true, true, okr,
                       okC, okC, okC && okr};
  float w[18];
  {
    float mx = 0.f;
#pragma unroll
    for (int n = 0; n < 9; ++n) { w[n] = ok0[n] ? lg[n] * SCALE : 0.f; mx = fmaxf(mx, w[n]); }
    float sum = 0.f;
#pragma unroll
    for (int n = 0; n < 9; ++n) { w[n] = __expf(w[n] - mx); sum += w[n]; }
    const float inv = 1.f / sum;
#pragma unroll
    for (int n = 0; n < 9; ++n) w[n] = ok0[n] ? w[n] * inv : 0.f;
  }
  {
    float mx = 0.f;
#pragma unroll
    for (int n = 0; n < 9; ++n) { w[9 + n] = ok1[n] ? lg[9 + n] * SCALE : 0.f; mx = fmaxf(mx, w[9 + n]); }
    float sum = 0.f;
#pragma unroll
    for (int n = 0; n < 9; ++n) { w[9 + n] = __expf(w[9 + n] - mx); sum += w[9 + n]; }
    const float inv = 1.f / sum;
#pragma unroll
    for (int n = 0; n < 9; ++n) w[9 + n] = ok1[n] ? w[9 + n] * inv : 0.f;
  }

  // ---- pass 2: 8 v slabs; f4 transpose writes; 32-ch half READOUTs ----
  const int row0 = r * 56 + x0;        // tbuf rows for px0 / px1

#define CONSV(S, cl)                                    \
  {                                                     \
    float o0[8], o1[8];                                 \
    _Pragma("unroll") for (int i = 0; i < 8; ++i) {     \
      const float2 A = va##S[i], B2 = vb##S[i], C = vc##S[i]; \
      const float tlA = tapLf(A.y),  trA = tapRf(A.x);  \
      const float tlB = tapLf(B2.y), trB = tapRf(B2.x); \
      const float tlC = tapLf(C.y),  trC = tapRf(C.x);  \
      float s0 = w[0] * tlA;                            \
      s0 = fmaf(w[1], A.x,  s0);                        \
      s0 = fmaf(w[2], A.y,  s0);                        \
      s0 = fmaf(w[3], tlB,  s0);                        \
      s0 = fmaf(w[4], B2.x, s0);                        \
      s0 = fmaf(w[5], B2.y, s0);                        \
      s0 = fmaf(w[6], tlC,  s0);                        \
      s0 = fmaf(w[7], C.x,  s0);                        \
      s0 = fmaf(w[8], C.y,  s0);                        \
      o0[i] = s0;                                       \
      float s1 = w[9] * A.x;                            \
      s1 = fmaf(w[10], A.y,  s1);                       \
      s1 = fmaf(w[11], trA,  s1);                       \
      s1 = fmaf(w[12], B2.x, s1);                       \
      s1 = fmaf(w[13], B2.y, s1);                       \
      s1 = fmaf(w[14], trB,  s1);                       \
      s1 = fmaf(w[15], C.x,  s1);                       \
      s1 = fmaf(w[16], C.y,  s1);                       \
      s1 = fmaf(w[17], trC,  s1);                       \
      o1[i] = s1;                                       \
    }                                                   \
    if (act) {                                          \
      *(float4*)&tbuf[row0 * TSTR + (cl)]           = make_float4(o0[0], o0[1], o0[2], o0[3]); \
      *(float4*)&tbuf[row0 * TSTR + (cl) + 4]       = make_float4(o0[4], o0[5], o0[6], o0[7]); \
      *(float4*)&tbuf[(row0 + 1) * TSTR + (cl)]     = make_float4(o1[0], o1[1], o1[2], o1[3]); \
      *(float4*)&tbuf[(row0 + 1) * TSTR + (cl) + 4] = make_float4(o1[4], o1[5], o1[6], o1[7]); \
    }                                                   \
  }

  // out base: rows y,y+1 are contiguous = 112 px
  float* __restrict__ ob =
      outg + ((long)(bh >> 3) * HW + (long)y * WW) * DTOT + (bh & 7) * HD;

  // read-out of one 32-ch half: 112 px x 8 f4 = 896 f4 = 14 exact rounds
#define READOUT(ch0)                                    \
  _Pragma("unroll") for (int rr = 0; rr < 14; ++rr) {   \
    const int g = rr * 64 + l;                          \
    const int pg = g >> 3, slot = g & 7;                \
    const float4 tv = *(const float4*)&tbuf[pg * TSTR + slot * 4]; \
    *(float4*)(ob + (long)pg * DTOT + (ch0) + slot * 4) = tv;      \
  }

  CONSV(A, 0);  LOADV(A, 16);
  CONSV(B, 8);  LOADV(B, 24);
  CONSV(A, 16); LOADV(A, 32);
  CONSV(B, 24); LOADV(B, 40);
  READOUT(0);
  CONSV(A, 0);  LOADV(A, 48);
  CONSV(B, 8);  LOADV(B, 56);
  CONSV(A, 16);
  CONSV(B, 24);
  READOUT(32);

#undef LOADK
#undef CONSK
#undef LOADV
#undef CONSV
#undef READOUT
}

} // namespace

extern "C" void kernel_launch(void* const* d_in, const int* in_sizes, int n_in,
                              void* d_out, int out_size, void* d_ws, size_t ws_size,
                              hipStream_t stream) {
  const float* q = (const float*)d_in[0];
  const float* k = (const float*)d_in[1];
  const float* v = (const float*)d_in[2];
  float* out = (float*)d_out;

  const int BH = in_sizes[0] / (HD * HW);  // B * 8 heads = 64
  dim3 grid(BH * NP);                       // 1792 = 8 * 224
  adda_fwd<<<grid, 64, 0, stream>>>(q, k, v, out);
}

// Round 23
// 34.993 us; speedup vs baseline: 1.1205x; 1.0859x over previous
//
#include <hip/hip_runtime.h>

// ADDA local attention, K=3, dilation=1, head_dim=64.
// q,k,v = [B=8, d=512, H=56, W=56] fp32 (channel-major), out = [B,H,W,512] fp32.
//
// R23 = R17 (best, 33.58 us) + NON-TEMPORAL output stores.
// Warm rocprof shows FETCH_SIZE ~76 MB from HBM every replay (~half the
// 154 MB input set) despite a 256 MB L3: the 51 MB output stream evicts
// input lines. nt stores keep the output from displacing inputs ->
// inputs stay L3-resident -> read latency drops HBM(~900cy)->L3.
// Everything else identical to R17: 2-row DPP waves, 3-deep 4-ch slab
// pipeline, XCD swizzle, full-512B output ownership, TSTR=36 transpose,
// zero-padded-unfold masking at softmax only.

namespace {

constexpr int HD = 64, HH = 56, WW = 56, HW = HH * WW;
constexpr int CS = HW, DTOT = 512;
constexpr float SCALE = 0.125f;
constexpr int NP   = HH / 2;   // 28 row-pairs
constexpr int TSTR = 36;       // px stride in transpose LDS

typedef float __attribute__((ext_vector_type(4))) f4v;

// value of this row at x-1 (lane i <- lane i-1): wave_shr:1 = 0x138
__device__ __forceinline__ float tapL(float v) {
  int i = __float_as_int(v);
  return __int_as_float(__builtin_amdgcn_update_dpp(i, i, 0x138, 0xF, 0xF, false));
}
// value of this row at x+1 (lane i <- lane i+1): wave_shl:1 = 0x130
__device__ __forceinline__ float tapR(float v) {
  int i = __float_as_int(v);
  return __int_as_float(__builtin_amdgcn_update_dpp(i, i, 0x130, 0xF, 0xF, false));
}

__global__ __launch_bounds__(64, 2)
void adda_fwd(const float* __restrict__ qg, const float* __restrict__ kg,
              const float* __restrict__ vg, float* __restrict__ outg) {
  __shared__ float tbuf[128 * TSTR];   // 18432 B (row y: 0..63, row y+1: 64..127)

  // XCD-aware bijective swizzle (nwg = 1792 = 8*224)
  int wg = (int)blockIdx.x;
  const int nwg = (int)gridDim.x;
  if ((nwg & 7) == 0) wg = (wg & 7) * (nwg >> 3) + (wg >> 3);

  const int pair = wg % NP;
  const int bh   = wg / NP;            // b*8 + head
  const int l    = (int)threadIdx.x;   // 0..63
  const int y    = pair * 2;           // rows y, y+1
  const int x    = l < WW ? l : WW - 1;  // lanes 56-63 clone x=55 (not stored)

  const long base = (long)bh * HD * HW;
  const int gy0 = (y > 0) ? y - 1 : 0;          // clamped; masked below
  const int gy3 = (y + 2 < HH) ? y + 2 : HH - 1;

  const float* __restrict__ qp0 = qg + base + (long)y * WW + x;
  const float* __restrict__ qp1 = qg + base + (long)(y + 1) * WW + x;
  const float* __restrict__ k0p = kg + base + (long)gy0 * WW + x;
  const float* __restrict__ k1p = kg + base + (long)y * WW + x;
  const float* __restrict__ k2p = kg + base + (long)(y + 1) * WW + x;
  const float* __restrict__ k3p = kg + base + (long)gy3 * WW + x;
  const float* __restrict__ v0p = vg + base + (long)gy0 * WW + x;
  const float* __restrict__ v1p = vg + base + (long)y * WW + x;
  const float* __restrict__ v2p = vg + base + (long)(y + 1) * WW + x;
  const float* __restrict__ v3p = vg + base + (long)gy3 * WW + x;

  float lg[18];
#pragma unroll
  for (int n = 0; n < 18; ++n) lg[n] = 0.f;

  // ---- 4-channel slabs, 3 rotating sets ----
  float q0A[4], q1A[4], a0A[4], a1A[4], a2A[4], a3A[4];
  float q0B[4], q1B[4], a0B[4], a1B[4], a2B[4], a3B[4];
  float q0C[4], q1C[4], a0C[4], a1C[4], a2C[4], a3C[4];

#define LOADK(S, cb)                                    \
  _Pragma("unroll") for (int i = 0; i < 4; ++i) {       \
    q0##S[i] = qp0[((cb) + i) * CS];                    \
    q1##S[i] = qp1[((cb) + i) * CS];                    \
    a0##S[i] = k0p[((cb) + i) * CS];                    \
    a1##S[i] = k1p[((cb) + i) * CS];                    \
    a2##S[i] = k2p[((cb) + i) * CS];                    \
    a3##S[i] = k3p[((cb) + i) * CS];                    \
  }
#define CONSK(S)                                        \
  _Pragma("unroll") for (int i = 0; i < 4; ++i) {       \
    const float t0l = tapL(a0##S[i]), t0r = tapR(a0##S[i]); \
    const float t1l = tapL(a1##S[i]), t1r = tapR(a1##S[i]); \
    const float t2l = tapL(a2##S[i]), t2r = tapR(a2##S[i]); \
    const float t3l = tapL(a3##S[i]), t3r = tapR(a3##S[i]); \
    const float q0 = q0##S[i], q1 = q1##S[i];           \
    lg[0]  = fmaf(q0, t0l,      lg[0]);                 \
    lg[1]  = fmaf(q0, a0##S[i], lg[1]);                 \
    lg[2]  = fmaf(q0, t0r,      lg[2]);                 \
    lg[3]  = fmaf(q0, t1l,      lg[3]);                 \
    lg[4]  = fmaf(q0, a1##S[i], lg[4]);                 \
    lg[5]  = fmaf(q0, t1r,      lg[5]);                 \
    lg[6]  = fmaf(q0, t2l,      lg[6]);                 \
    lg[7]  = fmaf(q0, a2##S[i], lg[7]);                 \
    lg[8]  = fmaf(q0, t2r,      lg[8]);                 \
    lg[9]  = fmaf(q1, t1l,      lg[9]);                 \
    lg[10] = fmaf(q1, a1##S[i], lg[10]);                \
    lg[11] = fmaf(q1, t1r,      lg[11]);                \
    lg[12] = fmaf(q1, t2l,      lg[12]);                \
    lg[13] = fmaf(q1, a2##S[i], lg[13]);                \
    lg[14] = fmaf(q1, t2r,      lg[14]);                \
    lg[15] = fmaf(q1, t3l,      lg[15]);                \
    lg[16] = fmaf(q1, a3##S[i], lg[16]);                \
    lg[17] = fmaf(q1, t3r,      lg[17]);                \
  }

  float b0A[4], b1A[4], b2A[4], b3A[4];
  float b0B[4], b1B[4], b2B[4], b3B[4];
  float b0C[4], b1C[4], b2C[4], b3C[4];
#define LOADV(S, cb)                                    \
  _Pragma("unroll") for (int i = 0; i < 4; ++i) {       \
    b0##S[i] = v0p[((cb) + i) * CS];                    \
    b1##S[i] = v1p[((cb) + i) * CS];                    \
    b2##S[i] = v2p[((cb) + i) * CS];                    \
    b3##S[i] = v3p[((cb) + i) * CS];                    \
  }

  // ---- pass 1: 16 k slabs, 3-deep ----
  LOADK(A, 0); LOADK(B, 4); LOADK(C, 8);
  CONSK(A); LOADK(A, 12);
  CONSK(B); LOADK(B, 16);
  CONSK(C); LOADK(C, 20);
  CONSK(A); LOADK(A, 24);
  CONSK(B); LOADK(B, 28);
  CONSK(C); LOADK(C, 32);
  CONSK(A); LOADK(A, 36);
  CONSK(B); LOADK(B, 40);
  CONSK(C); LOADK(C, 44);
  CONSK(A); LOADK(A, 48);
  CONSK(B); LOADK(B, 52);
  CONSK(C); LOADK(C, 56);
  CONSK(A); LOADK(A, 60);
  CONSK(B); LOADV(A, 0);
  CONSK(C); LOADV(B, 4);
  CONSK(A); LOADV(C, 8);

  // ---- softmax, both rows (zero-padded unfold: OOB logit = exact 0) ----
  const bool okl = x > 0, okr = x < WW - 1;
  const bool okt0 = y > 0;
  const bool okb1 = (y + 2) < HH;
  const bool ok[18] = {
    okt0 && okl, okt0, okt0 && okr,
    okl,         true, okr,
    okl,         true, okr,
    okl,         true, okr,
    okl,         true, okr,
    okb1 && okl, okb1, okb1 && okr};
  float w[18];
#pragma unroll
  for (int e = 0; e < 2; ++e) {
    float mx = 0.f;
#pragma unroll
    for (int n = 0; n < 9; ++n) {
      w[e * 9 + n] = ok[e * 9 + n] ? lg[e * 9 + n] * SCALE : 0.f;
      mx = fmaxf(mx, w[e * 9 + n]);
    }
    float sum = 0.f;
#pragma unroll
    for (int n = 0; n < 9; ++n) { w[e * 9 + n] = __expf(w[e * 9 + n] - mx); sum += w[e * 9 + n]; }
    const float inv = 1.f / sum;
#pragma unroll
    for (int n = 0; n < 9; ++n)
      w[e * 9 + n] = ok[e * 9 + n] ? w[e * 9 + n] * inv : 0.f;  // OOB v = 0
  }

  // ---- pass 2: 16 v slabs, 3-deep; per-slab f4 transpose store ----
  float* __restrict__ ob =
      outg + ((long)(bh >> 3) * HW + (long)y * WW) * DTOT + (bh & 7) * HD;

#define CONSV(S, sl)                                    \
  {                                                     \
    float o0[4], o1[4];                                 \
    _Pragma("unroll") for (int i = 0; i < 4; ++i) {     \
      const float t0l = tapL(b0##S[i]), t0r = tapR(b0##S[i]); \
      const float t1l = tapL(b1##S[i]), t1r = tapR(b1##S[i]); \
      const float t2l = tapL(b2##S[i]), t2r = tapR(b2##S[i]); \
      const float t3l = tapL(b3##S[i]), t3r = tapR(b3##S[i]); \
      float a = w[0] * t0l;                             \
      a = fmaf(w[1], b0##S[i], a);                      \
      a = fmaf(w[2], t0r, a);                           \
      a = fmaf(w[3], t1l, a);                           \
      a = fmaf(w[4], b1##S[i], a);                      \
      a = fmaf(w[5], t1r, a);                           \
      a = fmaf(w[6], t2l, a);                           \
      a = fmaf(w[7], b2##S[i], a);                      \
      a = fmaf(w[8], t2r, a);                           \
      o0[i] = a;                                        \
      float c = w[9] * t1l;                             \
      c = fmaf(w[10], b1##S[i], c);                     \
      c = fmaf(w[11], t1r, c);                          \
      c = fmaf(w[12], t2l, c);                          \
      c = fmaf(w[13], b2##S[i], c);                     \
      c = fmaf(w[14], t2r, c);                          \
      c = fmaf(w[15], t3l, c);                          \
      c = fmaf(w[16], b3##S[i], c);                     \
      c = fmaf(w[17], t3r, c);                          \
      o1[i] = c;                                        \
    }                                                   \
    *(float4*)&tbuf[l * TSTR + (sl) * 4] =              \
        make_float4(o0[0], o0[1], o0[2], o0[3]);        \
    *(float4*)&tbuf[(64 + l) * TSTR + (sl) * 4] =       \
        make_float4(o1[0], o1[1], o1[2], o1[3]);        \
  }
  // read-out of one 32-ch run for both rows: 112 px x 8 f4 = 14 exact rounds.
  // NON-TEMPORAL stores: keep the 51 MB output stream from evicting the
  // 154 MB input set out of L3 (warm FETCH_SIZE was ~76 MB = thrash).
#define READOUT(ch0)                                    \
  _Pragma("unroll") for (int r = 0; r < 14; ++r) {      \
    const int g = r * 64 + l;                           \
    const int pxl = g >> 3, slot = g & 7;               \
    const int lrow = pxl + ((pxl >= 56) ? 8 : 0);       \
    const f4v tv = *(const f4v*)&tbuf[lrow * TSTR + slot * 4]; \
    __builtin_nontemporal_store(tv,                     \
        (f4v*)(ob + (long)pxl * DTOT + (ch0) + slot * 4));     \
  }

  CONSV(A, 0); LOADV(A, 12);
  CONSV(B, 1); LOADV(B, 16);
  CONSV(C, 2); LOADV(C, 20);
  CONSV(A, 3); LOADV(A, 24);
  CONSV(B, 4); LOADV(B, 28);
  CONSV(C, 5); LOADV(C, 32);
  CONSV(A, 6); LOADV(A, 36);
  CONSV(B, 7); LOADV(B, 40);
  READOUT(0);
  CONSV(C, 0); LOADV(C, 44);
  CONSV(A, 1); LOADV(A, 48);
  CONSV(B, 2); LOADV(B, 52);
  CONSV(C, 3); LOADV(C, 56);
  CONSV(A, 4); LOADV(A, 60);
  CONSV(B, 5);
  CONSV(C, 6);
  CONSV(A, 7);
  READOUT(32);

#undef LOADK
#undef CONSK
#undef LOADV
#undef CONSV
#undef READOUT
}

} // namespace

extern "C" void kernel_launch(void* const* d_in, const int* in_sizes, int n_in,
                              void* d_out, int out_size, void* d_ws, size_t ws_size,
                              hipStream_t stream) {
  const float* q = (const float*)d_in[0];
  const float* k = (const float*)d_in[1];
  const float* v = (const float*)d_in[2];
  float* out = (float*)d_out;

  const int BH = in_sizes[0] / (HD * HW);  // B * 8 heads = 64
  dim3 grid(BH * NP);                       // 1792 = 8 * 224
  adda_fwd<<<grid, 64, 0, stream>>>(q, k, v, out);
}